// Round 8
// baseline (172.460 us; speedup 1.0000x reference)
//
#include <hip/hip_runtime.h>
#include <hip/hip_bf16.h>

// Head: out[b,t,h] = softmax_causal( (x@Wq)(x@Wk)^T * 6^-0.5 ) @ (x@Wv)
// B=512 T=128 C=384 H=64. One block per b, bf16 MFMA 16x16x32.
//
// V8 = V5 + DIAGNOSTIC phase-2 duplication (semantics-preserving ablation).
//  - Four different phase-1 staging schemes (V2/V3/V5/V7) all land ~55-60us
//    -> phase-1 protocol is not the dominant cost; need the phase split.
//  - QK^T+softmax run TWICE (idempotent: sacc re-zeroed, reads intact Qs/Ks;
//    rep-1 results kept live via asm "v" sinks per rule 17, "memory" clobber
//    forces rep-2 LDS reads to re-issue). P-write once. PV+store TWICE
//    (idempotent: same values to same addresses).
//  - Marginal dur vs V5's 168.2us = real phase-2 cost, measured in situ.

#define B_ 512
#define T_ 128
#define C_ 384
#define H_ 64

typedef __bf16 bf16;
typedef __attribute__((ext_vector_type(8))) __bf16 bf16x8;
typedef __attribute__((ext_vector_type(4))) __bf16 bf16x4;
typedef __attribute__((ext_vector_type(4))) float f32x4;

#define GLOAD_LDS16(g, l)                                                     \
    __builtin_amdgcn_global_load_lds(                                         \
        (const __attribute__((address_space(1))) void*)(g),                   \
        (__attribute__((address_space(3))) void*)(l), 16, 0, 0)

// ---------------- pre-kernel: W -> bf16 W^T in MFMA B-fragment order --------
__global__ void build_wt(const float* __restrict__ Wq, const float* __restrict__ Wk,
                         const float* __restrict__ Wv, bf16* __restrict__ Wt)
{
    int t = blockIdx.x * 256 + threadIdx.x;
    if (t >= 12 * 12 * 64) return;
    int lane = t & 63;
    int tn   = (t >> 6) % 12;
    int kc   = t / (12 * 64);
    int lm = lane & 15, quad = lane >> 4;
    int n = tn * 16 + lm;
    int j = n >> 6, h = n & 63;
    const float* Wp = (j == 0) ? Wq : (j == 1) ? Wk : Wv;
    int k0 = kc * 32 + quad * 8;
    bf16x8 v;
#pragma unroll
    for (int e = 0; e < 8; ++e) v[e] = (bf16)Wp[(k0 + e) * H_ + h];
    *(bf16x8*)&Wt[t * 8] = v;
}

// LDS (57344 bytes -> 2 blocks/CU):
//  k-loop: 2 x 28KB buffers {x 16KB swizzled fp32, Wt 12KB linear}
//  after:  Qs [0,8192) elems, Ks [8192,16384), Vts [16384,24576),
//          Ps aliases [0,16384)

__launch_bounds__(512, 4)
__global__ void head_fused(const float* __restrict__ x,
                           const bf16* __restrict__ Wt,
                           float* __restrict__ out)
{
    __shared__ __align__(16) bf16 lds[28672];
    bf16* Qs  = lds;
    bf16* Ks  = lds + 8192;
    bf16* Vts = lds + 16384;
    bf16* Ps  = lds;

    const int tid  = threadIdx.x;
    const int w    = tid >> 6;     // wave 0..7
    const int lane = tid & 63;
    const int lm   = lane & 15;
    const int quad = lane >> 4;
    const int mg   = w >> 2;
    const int ng   = w & 3;
    const int b    = blockIdx.x;

    const float* xb = x + (size_t)b * (T_ * C_);

    // ================= Phase 1: QKV = x[b] @ [Wq|Wk|Wv] =================
    f32x4 acc[4][3];
#pragma unroll
    for (int mf = 0; mf < 4; ++mf)
#pragma unroll
        for (int nf = 0; nf < 3; ++nf) acc[mf][nf] = (f32x4){0.f, 0.f, 0.f, 0.f};

    const int r0 = tid >> 3, r1 = (tid + 512) >> 3;
    const float* gx0 = xb + (size_t)r0 * C_ + (((tid & 7) ^ (r0 & 7)) * 4);
    const float* gx1 = xb + (size_t)r1 * C_ + (((tid & 7) ^ (r1 & 7)) * 4);
    char* lx0 = (char*)lds + w * 1024;
    char* lx1 = (char*)lds + 8192 + w * 1024;
    const char* gwt = (const char*)Wt;
    char* lw0 = (char*)lds + 16384 + w * 1024;
    char* lw1 = (char*)lds + 16384 + 8192 + w * 1024;

    auto STAGE = [&](int kc) {
        int bo = (kc & 1) * 28672;
        GLOAD_LDS16(gx0 + kc * 32, lx0 + bo);
        GLOAD_LDS16(gx1 + kc * 32, lx1 + bo);
        GLOAD_LDS16(gwt + (size_t)kc * 12288 + tid * 16, lw0 + bo);
        if (w < 4)
            GLOAD_LDS16(gwt + (size_t)kc * 12288 + 8192 + tid * 16, lw1 + bo);
    };

    STAGE(0);
    asm volatile("s_waitcnt vmcnt(0)" ::: "memory");
    __builtin_amdgcn_s_barrier();

#pragma unroll
    for (int kc = 0; kc < 12; ++kc) {
        if (kc < 11) STAGE(kc + 1);

        const float* xc = (const float*)((const char*)lds + (kc & 1) * 28672);
        const bf16*  wc = (const bf16*)((const char*)lds + (kc & 1) * 28672 + 16384);

        bf16x8 afr[4];
#pragma unroll
        for (int mf = 0; mf < 4; ++mf) {
            int row = 64 * mg + 16 * mf + lm;
            int p0 = (2 * quad) ^ (row & 7);
            int p1 = (2 * quad + 1) ^ (row & 7);
            f32x4 va = *(const f32x4*)(xc + row * 32 + p0 * 4);
            f32x4 vb = *(const f32x4*)(xc + row * 32 + p1 * 4);
            afr[mf] = (bf16x8){(bf16)va[0], (bf16)va[1], (bf16)va[2], (bf16)va[3],
                               (bf16)vb[0], (bf16)vb[1], (bf16)vb[2], (bf16)vb[3]};
        }
#pragma unroll
        for (int nf = 0; nf < 3; ++nf) {
            bf16x8 bfr = *(const bf16x8*)(wc + (3 * ng + nf) * 512 + lane * 8);
#pragma unroll
            for (int mf = 0; mf < 4; ++mf)
                acc[mf][nf] =
                    __builtin_amdgcn_mfma_f32_16x16x32_bf16(afr[mf], bfr, acc[mf][nf], 0, 0, 0);
        }

        if (kc < 11) {
            asm volatile("s_waitcnt vmcnt(0)" ::: "memory");
            __builtin_amdgcn_s_barrier();
        }
    }
    __syncthreads();   // staging dies; Q/K/Vt region becomes live

    // epilogue: Q,K row-major [t][h]; V transposed [h][t]; all swizzled bf16
#pragma unroll
    for (int mf = 0; mf < 4; ++mf) {
#pragma unroll
        for (int nf = 0; nf < 3; ++nf) {
            int tn = 3 * ng + nf;
            int gn = 16 * tn + lm;
            int j = gn >> 6, h = gn & 63;
            int m0 = 64 * mg + 16 * mf + quad * 4;
            if (j == 2) {
                bf16x4 v4 = {(bf16)acc[mf][nf][0], (bf16)acc[mf][nf][1],
                             (bf16)acc[mf][nf][2], (bf16)acc[mf][nf][3]};
                int pc = (m0 & 7) | ((((m0 >> 3) ^ (h & 15)) & 15) << 3);
                *(bf16x4*)&Vts[h * 128 + pc] = v4;
            } else {
                bf16* dst = (j == 0) ? Qs : Ks;
#pragma unroll
                for (int r = 0; r < 4; ++r) {
                    int m = m0 + r;
                    int pc = (h & 7) | ((((h >> 3) ^ (m & 7)) & 7) << 3);
                    dst[m * 64 + pc] = (bf16)acc[mf][nf][r];
                }
            }
        }
    }
    __syncthreads();

    // ================= Phase 2: attention =================
    const float SCALE = 0.40824829046386307f;  // 6^-0.5
    const int tm = w;
    const int mrow = 16 * tm + lm;

    // ---- S = Q K^T + softmax, run TWICE (diagnostic; idempotent) ----
    f32x4 sacc[8];
#pragma unroll
    for (int rep = 0; rep < 2; ++rep) {
#pragma unroll
        for (int t = 0; t < 8; ++t) sacc[t] = (f32x4){0.f, 0.f, 0.f, 0.f};

        bf16x8 qa[2];
#pragma unroll
        for (int ks = 0; ks < 2; ++ks) {
            int phys = ((ks * 4 + quad) ^ (mrow & 7)) & 7;
            qa[ks] = *(const bf16x8*)&Qs[mrow * 64 + phys * 8];
        }
#pragma unroll
        for (int tn = 0; tn < 8; ++tn) {
            if (tn <= tm) {
                int nrow = 16 * tn + lm;
#pragma unroll
                for (int ks = 0; ks < 2; ++ks) {
                    int phys = ((ks * 4 + quad) ^ (nrow & 7)) & 7;
                    bf16x8 kb = *(const bf16x8*)&Ks[nrow * 64 + phys * 8];
                    sacc[tn] =
                        __builtin_amdgcn_mfma_f32_16x16x32_bf16(qa[ks], kb, sacc[tn], 0, 0, 0);
                }
            }
        }

#pragma unroll
        for (int r = 0; r < 4; ++r) {
            int m = 16 * tm + quad * 4 + r;
            float mx = -1e30f;
#pragma unroll
            for (int tn = 0; tn < 8; ++tn) {
                if (tn <= tm) {
                    int n = 16 * tn + lm;
                    float v = (n <= m) ? sacc[tn][r] * SCALE : -1e30f;
                    sacc[tn][r] = v;
                    mx = fmaxf(mx, v);
                }
            }
#pragma unroll
            for (int off = 1; off < 16; off <<= 1) mx = fmaxf(mx, __shfl_xor(mx, off, 16));
            float sum = 0.f;
#pragma unroll
            for (int tn = 0; tn < 8; ++tn) {
                if (tn <= tm) {
                    float e = __expf(sacc[tn][r] - mx);
                    sacc[tn][r] = e;
                    sum += e;
                }
            }
#pragma unroll
            for (int off = 1; off < 16; off <<= 1) sum += __shfl_xor(sum, off, 16);
            float inv = 1.f / sum;
#pragma unroll
            for (int tn = 0; tn < 8; ++tn) {
                if (tn <= tm) sacc[tn][r] *= inv;
            }
        }

        if (rep == 0) {
            // keep rep-0 results live (rule 17: defeat DCE), force rep-1
            // LDS reads to re-issue ("memory").
#pragma unroll
            for (int t = 0; t < 8; ++t)
                asm volatile("" :: "v"(sacc[t][0]), "v"(sacc[t][1]),
                                   "v"(sacc[t][2]), "v"(sacc[t][3]));
            asm volatile("" ::: "memory");
        }
    }

    __syncthreads();  // everyone done reading Qs/Ks; Ps aliases them

    // write P (bf16, swizzled); ONCE
#pragma unroll
    for (int tn = 0; tn < 8; ++tn) {
        if (tn <= tm) {
            int n = 16 * tn + lm;
#pragma unroll
            for (int r = 0; r < 4; ++r) {
                int m = 16 * tm + quad * 4 + r;
                int pc = (n & 7) | ((((n >> 3) ^ (m & 15)) & 15) << 3);
                Ps[m * 128 + pc] = (bf16)sacc[tn][r];
            }
        }
    }
    if ((tm & 1) == 0) {
        int m = 16 * tm + lm;
        int c0 = 16 * (tm + 1) + quad * 4;
        int pc = (c0 & 7) | ((((c0 >> 3) ^ (m & 15)) & 15) << 3);
        *(bf16x4*)&Ps[m * 128 + pc] =
            (bf16x4){(bf16)0.f, (bf16)0.f, (bf16)0.f, (bf16)0.f};
    }

    // ---- O = P @ V + store, run TWICE (diagnostic; idempotent) ----
    float* ob = out + (size_t)b * (T_ * H_);
#pragma unroll
    for (int rep = 0; rep < 2; ++rep) {
        f32x4 oacc[4];
#pragma unroll
        for (int t = 0; t < 4; ++t) oacc[t] = (f32x4){0.f, 0.f, 0.f, 0.f};

        const int nks = (tm + 2) >> 1;
        for (int ks = 0; ks < nks; ++ks) {  // wave-uniform bound
            int unit = ks * 4 + quad;
            int phys = (unit ^ (mrow & 15)) & 15;
            bf16x8 pa = *(const bf16x8*)&Ps[mrow * 128 + phys * 8];
#pragma unroll
            for (int th = 0; th < 4; ++th) {
                int hrow = 16 * th + lm;
                int ph2 = (unit ^ (hrow & 15)) & 15;
                bf16x8 vb = *(const bf16x8*)&Vts[hrow * 128 + ph2 * 8];
                oacc[th] =
                    __builtin_amdgcn_mfma_f32_16x16x32_bf16(pa, vb, oacc[th], 0, 0, 0);
            }
        }

#pragma unroll
        for (int th = 0; th < 4; ++th) {
            int h = 16 * th + lm;
#pragma unroll
            for (int r = 0; r < 4; ++r) {
                int m = 16 * tm + quad * 4 + r;
                ob[m * 64 + h] = oacc[th][r];
            }
        }
        if (rep == 0) asm volatile("" ::: "memory");  // force re-execution
    }
}

extern "C" void kernel_launch(void* const* d_in, const int* in_sizes, int n_in,
                              void* d_out, int out_size, void* d_ws, size_t ws_size,
                              hipStream_t stream) {
    const float* x  = (const float*)d_in[0];
    const float* Wq = (const float*)d_in[1];
    const float* Wk = (const float*)d_in[2];
    const float* Wv = (const float*)d_in[3];
    float* o = (float*)d_out;
    bf16* Wt = (bf16*)d_ws;   // needs 147456 bytes
    build_wt<<<dim3(36), dim3(256), 0, stream>>>(Wq, Wk, Wv, Wt);
    head_fused<<<dim3(B_), dim3(512), 0, stream>>>(x, Wt, o);
}